// Round 5
// baseline (47.362 us; speedup 1.0000x reference)
//
#include <hip/hip_runtime.h>
#include <hip/hip_bf16.h>

typedef __bf16 bf16;
typedef __bf16 bf16x4 __attribute__((ext_vector_type(4)));
typedef __bf16 bf16x8 __attribute__((ext_vector_type(8)));
typedef float f32x4 __attribute__((ext_vector_type(4)));

#define NEGV -9.0e15f

#define GLD16(gp, lp)                                                    \
  __builtin_amdgcn_global_load_lds(                                     \
      (const __attribute__((address_space(1))) void*)(gp),              \
      (__attribute__((address_space(3))) void*)(lp), 16, 0, 0)

// ---------------- prep: x->bf16, Wqkv^T (col-reordered), Wo^T ----------------
// Wqkv column n = h*192 + sel*64 + d  ->  n' = sel*512 + h*64 + d

__global__ __launch_bounds__(256) void k_prep(
    const float* __restrict__ x, const float* __restrict__ Wqkv, const float* __restrict__ Wo,
    bf16* __restrict__ xb, bf16* __restrict__ WqkvT, bf16* __restrict__ WoT) {
  const int bid = blockIdx.x, tid = threadIdx.x;
  if (bid < 2048) {               // x convert: 2048 * 1024 floats
    int i = bid * 1024 + tid * 4;
    float4 v = *(const float4*)(x + i);
    bf16x4 o;
    o[0] = (bf16)v.x; o[1] = (bf16)v.y; o[2] = (bf16)v.z; o[3] = (bf16)v.w;
    *(bf16x4*)(xb + i) = o;
    return;
  }
  __shared__ float tl[32][33];
  const float* src; bf16* dst; int N, t; bool remap;
  if (bid < 2816) { t = bid - 2048; src = Wqkv; dst = WqkvT; N = 1536; remap = true; }
  else            { t = bid - 2816; src = Wo;   dst = WoT;   N = 512;  remap = false; }
  const int tk = t & 15, tn = t >> 4;
  const int c = tid & 31, r0 = tid >> 5;
  for (int rr = 0; rr < 4; ++rr) {
    int row = r0 + rr * 8;
    tl[row][c] = src[(size_t)(tk * 32 + row) * N + tn * 32 + c];
  }
  __syncthreads();
  for (int rr = 0; rr < 4; ++rr) {
    int row = r0 + rr * 8;
    int nn = tn * 32 + row;
    int np = nn;
    if (remap) {
      int h = nn / 192, r2 = nn - h * 192, sel = r2 >> 6, d = r2 & 63;
      np = sel * 512 + h * 64 + d;
    }
    dst[(size_t)np * 512 + tk * 32 + c] = (bf16)tl[c][row];
  }
}

// ---------------- GEMM 1: qkv = x @ Wqkv + b -> Q/K/V^T ----------------
// 2-wave blocks, BM=128 (wave M-split), BN=64. Wave tile 64x64 (acc 4x4).
// Grid (32,24) = 768 = 3/CU. LDS swizzled via pre-swizzled gld_lds source.

__global__ __launch_bounds__(128) void k_gemm_qkv(
    const bf16* __restrict__ A, const bf16* __restrict__ BT, const float* __restrict__ bias,
    bf16* __restrict__ Qb, bf16* __restrict__ Kb, bf16* __restrict__ VTb) {
  __shared__ __align__(16) char As[16384];   // [128 rows][64 bf16] (col-swizzled)
  __shared__ __align__(16) char Bs[8192];    // [64 rows][64 bf16]
  const int m0 = blockIdx.x * 128, n0 = blockIdx.y * 64;
  const int sel = blockIdx.y >> 3;           // 0=Q 1=K 2=V
  const bool isV = (sel == 2);
  const int tid = threadIdx.x, wave = tid >> 6, lane = tid & 63;
  const int lr = lane & 15, lg = lane >> 4;
  const int wr = wave * 64;
  const int srow = lane >> 3;
  const int srcsw = ((lane & 7) ^ (srow & 7)) << 4;   // pre-swizzled source col
  const int kxor = (lr & 7) << 4;                      // read-side un-swizzle
  const char* Ab = (const char*)A;
  const char* Bb = (const char*)BT;
  f32x4 acc[4][4] = {};

  for (int kt = 0; kt < 512; kt += 64) {
    __syncthreads();
#pragma unroll
    for (int t = 0; t < 8; ++t) {
      int chunk = wave * 8 + t;                        // 16 chunks x 8 rows
      GLD16(Ab + (size_t)(m0 + chunk * 8 + srow) * 1024 + kt * 2 + srcsw,
            As + chunk * 1024);
    }
#pragma unroll
    for (int t = 0; t < 4; ++t) {
      int chunk = wave * 4 + t;                        // 8 chunks
      GLD16(Bb + (size_t)(n0 + chunk * 8 + srow) * 1024 + kt * 2 + srcsw,
            Bs + chunk * 1024);
    }
    __syncthreads();
#pragma unroll
    for (int kk = 0; kk < 2; ++kk) {
      bf16x8 af[4], bfr[4];
      int colb = kk * 64 + lg * 16;
#pragma unroll
      for (int m = 0; m < 4; ++m)
        af[m] = *(const bf16x8*)(As + (wr + m * 16 + lr) * 128 + (colb ^ kxor));
#pragma unroll
      for (int n = 0; n < 4; ++n)
        bfr[n] = *(const bf16x8*)(Bs + (n * 16 + lr) * 128 + (colb ^ kxor));
      if (!isV) {
#pragma unroll
        for (int m = 0; m < 4; ++m)
#pragma unroll
          for (int n = 0; n < 4; ++n)
            acc[m][n] = __builtin_amdgcn_mfma_f32_16x16x32_bf16(af[m], bfr[n], acc[m][n], 0, 0, 0);
      } else {
#pragma unroll
        for (int m = 0; m < 4; ++m)
#pragma unroll
          for (int n = 0; n < 4; ++n)
            acc[m][n] = __builtin_amdgcn_mfma_f32_16x16x32_bf16(bfr[n], af[m], acc[m][n], 0, 0, 0);
      }
    }
  }

  if (!isV) {
    bf16* Dst = sel ? Kb : Qb;
    float bv[4]; int hh[4], dd[4];
#pragma unroll
    for (int n = 0; n < 4; ++n) {
      int gn = n0 + n * 16 + lr;
      hh[n] = (gn >> 6) & 7; dd[n] = gn & 63;
      bv[n] = bias[hh[n] * 192 + sel * 64 + dd[n]];
    }
#pragma unroll
    for (int m = 0; m < 4; ++m)
#pragma unroll
      for (int r = 0; r < 4; ++r) {
        int gm = m0 + wr + m * 16 + lg * 4 + r;
        int b = gm >> 11, s = gm & 2047;
#pragma unroll
        for (int n = 0; n < 4; ++n) {
          float v = acc[m][n][r] + bv[n];
          Dst[((size_t)(b * 8 + hh[n]) * 2048 + s) * 64 + dd[n]] = (bf16)v;
        }
      }
  } else {
    // swapped: C row = weight col n', col = x-row s (contiguous over lr)
#pragma unroll
    for (int m = 0; m < 4; ++m) {
      int gm = m0 + wr + m * 16 + lr;
      int b = gm >> 11, s = gm & 2047;
#pragma unroll
      for (int n = 0; n < 4; ++n)
#pragma unroll
        for (int r = 0; r < 4; ++r) {
          int gn = n0 + n * 16 + lg * 4 + r;
          int h = (gn >> 6) & 7, d = gn & 63;
          float v = acc[m][n][r] + bias[h * 192 + 128 + d];
          VTb[((size_t)(b * 8 + h) * 64 + d) * 2048 + s] = (bf16)v;
        }
    }
  }
}

// ---------------- attention ----------------
// grid (32, 16), 256 threads (4 waves). GLD16 staging (pre-swizzled source),
// no max-subtraction (scores bounded), additive padding mask.

__global__ __launch_bounds__(256) void k_attn(
    const bf16* __restrict__ Qb, const bf16* __restrict__ Kb, const bf16* __restrict__ VTb,
    const int* __restrict__ pmask, bf16* __restrict__ AO) {
  __shared__ __align__(16) char Qs[64 * 128];
  __shared__ __align__(16) char Ks[128 * 128];
  __shared__ __align__(16) char VTs[64 * 256];
  __shared__ __align__(16) char Ps[64 * 256];
  __shared__ float pmk[128];   // 0 = valid key, NEGV = masked

  const int qb = blockIdx.x, bh = blockIdx.y;
  const int b = bh >> 3, h = bh & 7;
  const int q0 = qb * 64, kstart = q0 - 32;
  const int tid = threadIdx.x, wave = tid >> 6, lane = tid & 63;
  const int lr = lane & 15, lg = lane >> 4;

  const bf16* Qg = Qb + (size_t)bh * (2048 * 64);
  const bf16* Kg = Kb + (size_t)bh * (2048 * 64);
  const bf16* Vg = VTb + (size_t)bh * (64 * 2048);

  const int srow8 = lane >> 3;
  const int srcsw8 = ((lane & 7) ^ (srow8 & 7)) << 4;
  // Q: 8 chunks x 8 rows x 128B
#pragma unroll
  for (int t = 0; t < 2; ++t) {
    int chunk = wave * 2 + t;
    int row = q0 + chunk * 8 + srow8;
    GLD16((const char*)Qg + (size_t)row * 128 + srcsw8, Qs + chunk * 1024);
  }
  // K: 16 chunks x 8 rows x 128B
#pragma unroll
  for (int t = 0; t < 4; ++t) {
    int chunk = wave * 4 + t;
    int row = chunk * 8 + srow8;
    int sk = kstart + row;
    sk = sk < 0 ? 0 : (sk > 2047 ? 2047 : sk);
    GLD16((const char*)Kg + (size_t)sk * 128 + srcsw8, Ks + chunk * 1024);
  }
  // V^T: 16 chunks x 4 rows x 256B
  {
    int srow4 = lane >> 4, cb = (lane & 15) << 4;
#pragma unroll
    for (int t = 0; t < 4; ++t) {
      int chunk = wave * 4 + t;
      int d = chunk * 4 + srow4;
      int csw = cb ^ ((d & 7) << 4);
      int sl = kstart + (csw >> 1);
      sl = sl < 0 ? 0 : (sl > 2040 ? 2040 : sl);
      GLD16((const char*)Vg + (size_t)d * 4096 + (size_t)sl * 2, VTs + chunk * 1024);
    }
  }
  if (tid < 128) {
    int sk = kstart + tid;
    pmk[tid] = (sk >= 0 && sk < 2048 && pmask[b * 2048 + sk] != 0) ? 0.0f : NEGV;
  }
  __syncthreads();

  // scores S = Q.K^T : 16 q-rows x 128 keys per wave
  const int kxor = (lr & 7) << 4;
  f32x4 sc[8] = {};
#pragma unroll
  for (int kk = 0; kk < 2; ++kk) {
    int colb = kk * 64 + lg * 16;
    int qrow = wave * 16 + lr;
    bf16x8 qf = *(const bf16x8*)(Qs + qrow * 128 + (colb ^ kxor));
#pragma unroll
    for (int nt = 0; nt < 8; ++nt) {
      int krow = nt * 16 + lr;
      bf16x8 kf = *(const bf16x8*)(Ks + krow * 128 + (colb ^ kxor));
      sc[nt] = __builtin_amdgcn_mfma_f32_16x16x32_bf16(qf, kf, sc[nt], 0, 0, 0);
    }
  }

  // mask + exp (no max-subtraction; scores bounded ~|3|)
  float msk[8];
#pragma unroll
  for (int nt = 0; nt < 8; ++nt) msk[nt] = pmk[nt * 16 + lr];
  float rsum[4] = {0.f, 0.f, 0.f, 0.f};
#pragma unroll
  for (int nt = 0; nt < 8; ++nt) {
    int j = nt * 16 + lr;
#pragma unroll
    for (int r = 0; r < 4; ++r) {
      int qrow = wave * 16 + lg * 4 + r;
      float v = fmaf(sc[nt][r], 0.125f, msk[nt]);
      v = ((unsigned)(j - qrow) <= 64u) ? v : NEGV;
      float p = __expf(v);
      sc[nt][r] = p;
      rsum[r] += p;
    }
  }
#pragma unroll
  for (int off = 1; off < 16; off <<= 1)
#pragma unroll
    for (int r = 0; r < 4; ++r)
      rsum[r] += __shfl_xor(rsum[r], off);
#pragma unroll
  for (int r = 0; r < 4; ++r) rsum[r] = fmaxf(rsum[r], 1e-30f);

  // unnormalized P -> LDS (bf16)
#pragma unroll
  for (int nt = 0; nt < 8; ++nt)
#pragma unroll
    for (int r = 0; r < 4; ++r) {
      int qrow = wave * 16 + lg * 4 + r;
      int colb = (nt * 16 + lr) * 2;
      *(bf16*)(Ps + qrow * 256 + (colb ^ ((qrow & 7) << 4))) = (bf16)sc[nt][r];
    }
  __syncthreads();

  // O = P.V : 16 q-rows x 64 d per wave, K=128
  f32x4 oacc[4] = {};
#pragma unroll
  for (int ks = 0; ks < 4; ++ks) {
    int colb = ks * 64 + lg * 16;
    int prow = wave * 16 + lr;
    bf16x8 pf = *(const bf16x8*)(Ps + prow * 256 + (colb ^ ((prow & 7) << 4)));
#pragma unroll
    for (int n = 0; n < 4; ++n) {
      int vrow = n * 16 + lr;
      bf16x8 vf = *(const bf16x8*)(VTs + vrow * 256 + (colb ^ ((vrow & 7) << 4)));
      oacc[n] = __builtin_amdgcn_mfma_f32_16x16x32_bf16(pf, vf, oacc[n], 0, 0, 0);
    }
  }

  float inv[4];
#pragma unroll
  for (int r = 0; r < 4; ++r) inv[r] = 1.0f / rsum[r];
#pragma unroll
  for (int r = 0; r < 4; ++r) {
    int qrow = wave * 16 + lg * 4 + r;
    float s2 = (pmk[32 + qrow] == 0.0f) ? inv[r] : 0.0f;
#pragma unroll
    for (int n = 0; n < 4; ++n)
      AO[(size_t)(b * 2048 + q0 + qrow) * 512 + h * 64 + n * 16 + lr] = (bf16)(oacc[n][r] * s2);
  }
}

// ---------------- GEMM 2: out = AO @ Wo + bo (fp32 out), BM=128 BN=64 ----------------

__global__ __launch_bounds__(256) void k_gemm_out(
    const bf16* __restrict__ A, const bf16* __restrict__ BT, const float* __restrict__ bias,
    float* __restrict__ C) {
  __shared__ __align__(16) char As[16384];
  __shared__ __align__(16) char Bs[8192];
  const int m0 = blockIdx.x * 128, n0 = blockIdx.y * 64;
  const int tid = threadIdx.x, wave = tid >> 6, lane = tid & 63;
  const int wr = (wave >> 1) * 64, wc = (wave & 1) * 32;
  const int lr = lane & 15, lg = lane >> 4;
  const int srow = lane >> 3;
  const int srcsw = ((lane & 7) ^ (srow & 7)) << 4;
  const int kxor = (lr & 7) << 4;
  const char* Ab = (const char*)A;
  const char* Bb = (const char*)BT;
  f32x4 acc[4][2] = {};

  for (int kt = 0; kt < 512; kt += 64) {
    __syncthreads();
#pragma unroll
    for (int t = 0; t < 4; ++t) {
      int chunk = wave * 4 + t;
      GLD16(Ab + (size_t)(m0 + chunk * 8 + srow) * 1024 + kt * 2 + srcsw,
            As + chunk * 1024);
    }
#pragma unroll
    for (int t = 0; t < 2; ++t) {
      int chunk = wave * 2 + t;
      GLD16(Bb + (size_t)(n0 + chunk * 8 + srow) * 1024 + kt * 2 + srcsw,
            Bs + chunk * 1024);
    }
    __syncthreads();
#pragma unroll
    for (int kk = 0; kk < 2; ++kk) {
      bf16x8 af[4], bfr[2];
      int colb = kk * 64 + lg * 16;
#pragma unroll
      for (int m = 0; m < 4; ++m)
        af[m] = *(const bf16x8*)(As + (wr + m * 16 + lr) * 128 + (colb ^ kxor));
#pragma unroll
      for (int n = 0; n < 2; ++n)
        bfr[n] = *(const bf16x8*)(Bs + (wc + n * 16 + lr) * 128 + (colb ^ kxor));
#pragma unroll
      for (int m = 0; m < 4; ++m)
#pragma unroll
        for (int n = 0; n < 2; ++n)
          acc[m][n] = __builtin_amdgcn_mfma_f32_16x16x32_bf16(af[m], bfr[n], acc[m][n], 0, 0, 0);
    }
  }

  float bv0 = bias[n0 + wc + lr], bv1 = bias[n0 + wc + 16 + lr];
#pragma unroll
  for (int m = 0; m < 4; ++m)
#pragma unroll
    for (int n = 0; n < 2; ++n)
#pragma unroll
      for (int r = 0; r < 4; ++r) {
        int gm = m0 + wr + m * 16 + lg * 4 + r;
        int gn = n0 + wc + n * 16 + lr;
        C[(size_t)gm * 512 + gn] = acc[m][n][r] + (n ? bv1 : bv0);
      }
}

// ---------------- launch ----------------

extern "C" void kernel_launch(void* const* d_in, const int* in_sizes, int n_in,
                              void* d_out, int out_size, void* d_ws, size_t ws_size,
                              hipStream_t stream) {
  const float* x     = (const float*)d_in[0];
  const int*   pmask = (const int*)d_in[1];
  const float* Wqkv  = (const float*)d_in[2];
  const float* bqkv  = (const float*)d_in[3];
  const float* Wo    = (const float*)d_in[4];
  const float* bo    = (const float*)d_in[5];
  float* out = (float*)d_out;

  char* ws = (char*)d_ws;
  bf16* xb    = (bf16*)(ws);                 // 4 MiB
  bf16* WqkvT = (bf16*)(ws + 4194304);       // 1.5 MiB (reordered)
  bf16* WoT   = (bf16*)(ws + 5767168);       // 0.5 MiB
  bf16* Qb    = (bf16*)(ws + 6291456);       // [b][h][s][d] 4 MiB
  bf16* Kb    = (bf16*)(ws + 10485760);      // [b][h][s][d] 4 MiB
  bf16* VTb   = (bf16*)(ws + 14680064);      // [b][h][d][s] 4 MiB
  bf16* AO    = (bf16*)(ws + 18874368);      // [b][s][h*d]  4 MiB

  k_prep<<<3072, 256, 0, stream>>>(x, Wqkv, Wo, xb, WqkvT, WoT);

  dim3 g1(32, 24);
  k_gemm_qkv<<<g1, 128, 0, stream>>>(xb, WqkvT, bqkv, Qb, Kb, VTb);

  dim3 ga(32, 16);
  k_attn<<<ga, 256, 0, stream>>>(Qb, Kb, VTb, pmask, AO);

  dim3 g2(32, 8);
  k_gemm_out<<<g2, 256, 0, stream>>>(AO, WoT, bo, out);
}

// Round 6
// 43.421 us; speedup vs baseline: 1.0908x; 1.0908x over previous
//
#include <hip/hip_runtime.h>
#include <hip/hip_bf16.h>

typedef __bf16 bf16;
typedef __bf16 bf16x4 __attribute__((ext_vector_type(4)));
typedef __bf16 bf16x8 __attribute__((ext_vector_type(8)));
typedef float f32x4 __attribute__((ext_vector_type(4)));

#define NEGV -9.0e15f

#define GLD16(gp, lp)                                                    \
  __builtin_amdgcn_global_load_lds(                                     \
      (const __attribute__((address_space(1))) void*)(gp),              \
      (__attribute__((address_space(3))) void*)(lp), 16, 0, 0)

// ---------------- prep: x->bf16, Wqkv^T (col-reordered), Wo^T ----------------
// Wqkv column n = h*192 + sel*64 + d  ->  n' = sel*512 + h*64 + d

__global__ __launch_bounds__(256) void k_prep(
    const float* __restrict__ x, const float* __restrict__ Wqkv, const float* __restrict__ Wo,
    bf16* __restrict__ xb, bf16* __restrict__ WqkvT, bf16* __restrict__ WoT) {
  const int bid = blockIdx.x, tid = threadIdx.x;
  if (bid < 2048) {               // x convert: 2048 * 1024 floats
    int i = bid * 1024 + tid * 4;
    float4 v = *(const float4*)(x + i);
    bf16x4 o;
    o[0] = (bf16)v.x; o[1] = (bf16)v.y; o[2] = (bf16)v.z; o[3] = (bf16)v.w;
    *(bf16x4*)(xb + i) = o;
    return;
  }
  __shared__ float tl[32][33];
  const float* src; bf16* dst; int N, t; bool remap;
  if (bid < 2816) { t = bid - 2048; src = Wqkv; dst = WqkvT; N = 1536; remap = true; }
  else            { t = bid - 2816; src = Wo;   dst = WoT;   N = 512;  remap = false; }
  const int tk = t & 15, tn = t >> 4;
  const int c = tid & 31, r0 = tid >> 5;
  for (int rr = 0; rr < 4; ++rr) {
    int row = r0 + rr * 8;
    tl[row][c] = src[(size_t)(tk * 32 + row) * N + tn * 32 + c];
  }
  __syncthreads();
  for (int rr = 0; rr < 4; ++rr) {
    int row = r0 + rr * 8;
    int nn = tn * 32 + row;
    int np = nn;
    if (remap) {
      int h = nn / 192, r2 = nn - h * 192, sel = r2 >> 6, d = r2 & 63;
      np = sel * 512 + h * 64 + d;
    }
    dst[(size_t)np * 512 + tk * 32 + c] = (bf16)tl[c][row];
  }
}

// ---------------- GEMM 1 (round-4 structure): BM=128, BN=64, 4 waves 64x32 ----------------
// Grid (32,24) = 768 = 3 blocks/CU = 12 waves/CU. sel = blockIdx.y>>3: 0=Q 1=K 2=V.
// V tiles: swapped-operand MFMA -> transposed in-register -> coalesced VT stores.

__global__ __launch_bounds__(256) void k_gemm_qkv(
    const bf16* __restrict__ A, const bf16* __restrict__ BT, const float* __restrict__ bias,
    bf16* __restrict__ Qb, bf16* __restrict__ Kb, bf16* __restrict__ VTb) {
  __shared__ __align__(16) char As[16384];   // [128 rows][64 bf16]
  __shared__ __align__(16) char Bs[8192];    // [64 rows][64 bf16]
  const int m0 = blockIdx.x * 128, n0 = blockIdx.y * 64;
  const int sel = blockIdx.y >> 3;
  const bool isV = (sel == 2);
  const int tid = threadIdx.x, wave = tid >> 6, lane = tid & 63;
  const int wr = (wave >> 1) * 64, wc = (wave & 1) * 32;
  const int lr = lane & 15, lg = lane >> 4;
  const int srow = lane >> 3, scolb = (lane & 7) << 4;
  const char* Ab = (const char*)A;
  const char* Bb = (const char*)BT;
  f32x4 acc[4][2] = {};

  for (int kt = 0; kt < 512; kt += 64) {
    __syncthreads();
    for (int t = 0; t < 4; ++t) {
      int chunk = wave * 4 + t;
      GLD16(Ab + (size_t)(m0 + chunk * 8 + srow) * 1024 + kt * 2 + scolb,
            As + chunk * 1024);
    }
    for (int t = 0; t < 2; ++t) {
      int chunk = wave * 2 + t;
      GLD16(Bb + (size_t)(n0 + chunk * 8 + srow) * 1024 + kt * 2 + scolb,
            Bs + chunk * 1024);
    }
    __syncthreads();
    for (int kk = 0; kk < 2; ++kk) {
      bf16x8 af[4], bfr[2];
      for (int m = 0; m < 4; ++m)
        af[m] = *(const bf16x8*)(As + (wr + m * 16 + lr) * 128 + kk * 64 + lg * 16);
      for (int n = 0; n < 2; ++n)
        bfr[n] = *(const bf16x8*)(Bs + (wc + n * 16 + lr) * 128 + kk * 64 + lg * 16);
      if (!isV) {
        for (int m = 0; m < 4; ++m)
          for (int n = 0; n < 2; ++n)
            acc[m][n] = __builtin_amdgcn_mfma_f32_16x16x32_bf16(af[m], bfr[n], acc[m][n], 0, 0, 0);
      } else {
        for (int m = 0; m < 4; ++m)
          for (int n = 0; n < 2; ++n)
            acc[m][n] = __builtin_amdgcn_mfma_f32_16x16x32_bf16(bfr[n], af[m], acc[m][n], 0, 0, 0);
      }
    }
  }

  if (!isV) {
    bf16* Dst = sel ? Kb : Qb;
    float bv[2]; int hh[2], dd[2];
    for (int n = 0; n < 2; ++n) {
      int gn = n0 + wc + n * 16 + lr;
      hh[n] = (gn >> 6) & 7; dd[n] = gn & 63;
      bv[n] = bias[hh[n] * 192 + sel * 64 + dd[n]];
    }
    for (int m = 0; m < 4; ++m)
      for (int r = 0; r < 4; ++r) {
        int gm = m0 + wr + m * 16 + lg * 4 + r;
        int b = gm >> 11, s = gm & 2047;
        for (int n = 0; n < 2; ++n) {
          float v = acc[m][n][r] + bv[n];
          Dst[((size_t)(b * 8 + hh[n]) * 2048 + s) * 64 + dd[n]] = (bf16)v;
        }
      }
  } else {
    for (int m = 0; m < 4; ++m) {
      int gm = m0 + wr + m * 16 + lr;
      int b = gm >> 11, s = gm & 2047;
      for (int n = 0; n < 2; ++n)
        for (int r = 0; r < 4; ++r) {
          int gn = n0 + wc + n * 16 + lg * 4 + r;
          int h = (gn >> 6) & 7, d = gn & 63;
          float v = acc[m][n][r] + bias[h * 192 + 128 + d];
          VTb[((size_t)(b * 8 + h) * 64 + d) * 2048 + s] = (bf16)v;
        }
    }
  }
}

// ---------------- attention (round-4 staging + round-5 softmax numerics) ----------------
// grid (32, 16), 256 threads (4 waves), each wave: 16 query rows.

__global__ __launch_bounds__(256) void k_attn(
    const bf16* __restrict__ Qb, const bf16* __restrict__ Kb, const bf16* __restrict__ VTb,
    const int* __restrict__ pmask, bf16* __restrict__ AO) {
  __shared__ __align__(16) char Qs[64 * 128];
  __shared__ __align__(16) char Ks[128 * 128];
  __shared__ __align__(16) char VTs[64 * 256];
  __shared__ __align__(16) char Ps[64 * 256];
  __shared__ float pmk[128];   // 0 = valid key, NEGV = masked

  const int qb = blockIdx.x, bh = blockIdx.y;
  const int b = bh >> 3, h = bh & 7;
  const int q0 = qb * 64, kstart = q0 - 32;
  const int tid = threadIdx.x, wave = tid >> 6, lane = tid & 63;
  const int lr = lane & 15, lg = lane >> 4;

  const bf16* Qg = Qb + (size_t)bh * (2048 * 64);
  const bf16* Kg = Kb + (size_t)bh * (2048 * 64);
  const bf16* Vg = VTb + (size_t)bh * (64 * 2048);

  for (int c = tid; c < 512; c += 256) {
    int row = c >> 3, colb = (c & 7) << 4;
    *(uint4*)(Qs + row * 128 + (colb ^ ((row & 7) << 4))) =
        *(const uint4*)((const char*)Qg + (size_t)(q0 + row) * 128 + colb);
  }
  for (int c = tid; c < 1024; c += 256) {
    int row = c >> 3, colb = (c & 7) << 4;
    int sk = kstart + row;
    sk = sk < 0 ? 0 : (sk > 2047 ? 2047 : sk);
    *(uint4*)(Ks + row * 128 + (colb ^ ((row & 7) << 4))) =
        *(const uint4*)((const char*)Kg + (size_t)sk * 128 + colb);
  }
  for (int c = tid; c < 1024; c += 256) {
    int d = c >> 4, colb = (c & 15) << 4;
    int sl = kstart + (colb >> 1);
    sl = sl < 0 ? 0 : (sl > 2040 ? 2040 : sl);
    *(uint4*)(VTs + d * 256 + (colb ^ ((d & 7) << 4))) =
        *(const uint4*)((const char*)Vg + (size_t)d * 4096 + (size_t)sl * 2);
  }
  if (tid < 128) {
    int sk = kstart + tid;
    pmk[tid] = (sk >= 0 && sk < 2048 && pmask[b * 2048 + sk] != 0) ? 0.0f : NEGV;
  }
  __syncthreads();

  // scores S = Q.K^T : 16 q-rows x 128 keys per wave
  f32x4 sc[8] = {};
  for (int kk = 0; kk < 2; ++kk) {
    int colb = kk * 64 + lg * 16;
    int qrow = wave * 16 + lr;
    bf16x8 qf = *(const bf16x8*)(Qs + qrow * 128 + (colb ^ ((qrow & 7) << 4)));
    for (int nt = 0; nt < 8; ++nt) {
      int krow = nt * 16 + lr;
      bf16x8 kf = *(const bf16x8*)(Ks + krow * 128 + (colb ^ ((krow & 7) << 4)));
      sc[nt] = __builtin_amdgcn_mfma_f32_16x16x32_bf16(qf, kf, sc[nt], 0, 0, 0);
    }
  }

  // mask + exp, no max-subtraction (scores bounded; exp(NEG)=0 exactly).
  // validated numerically in round 5 (identical absmax).
  float msk[8];
#pragma unroll
  for (int nt = 0; nt < 8; ++nt) msk[nt] = pmk[nt * 16 + lr];
  float rsum[4] = {0.f, 0.f, 0.f, 0.f};
#pragma unroll
  for (int nt = 0; nt < 8; ++nt) {
    int j = nt * 16 + lr;
#pragma unroll
    for (int r = 0; r < 4; ++r) {
      int qrow = wave * 16 + lg * 4 + r;
      float v = fmaf(sc[nt][r], 0.125f, msk[nt]);
      v = ((unsigned)(j - qrow) <= 64u) ? v : NEGV;
      float p = __expf(v);
      sc[nt][r] = p;
      rsum[r] += p;
    }
  }
#pragma unroll
  for (int off = 1; off < 16; off <<= 1)
#pragma unroll
    for (int r = 0; r < 4; ++r)
      rsum[r] += __shfl_xor(rsum[r], off);
#pragma unroll
  for (int r = 0; r < 4; ++r) rsum[r] = fmaxf(rsum[r], 1e-30f);

  // unnormalized P -> LDS (bf16)
#pragma unroll
  for (int nt = 0; nt < 8; ++nt)
#pragma unroll
    for (int r = 0; r < 4; ++r) {
      int qrow = wave * 16 + lg * 4 + r;
      int colb = (nt * 16 + lr) * 2;
      *(bf16*)(Ps + qrow * 256 + (colb ^ ((qrow & 7) << 4))) = (bf16)sc[nt][r];
    }
  __syncthreads();

  // O = P.V : 16 q-rows x 64 d per wave, K=128
  f32x4 oacc[4] = {};
  for (int ks = 0; ks < 4; ++ks) {
    int colb = ks * 64 + lg * 16;
    int prow = wave * 16 + lr;
    bf16x8 pf = *(const bf16x8*)(Ps + prow * 256 + (colb ^ ((prow & 7) << 4)));
    for (int n = 0; n < 4; ++n) {
      int vrow = n * 16 + lr;
      bf16x8 vf = *(const bf16x8*)(VTs + vrow * 256 + (colb ^ ((vrow & 7) << 4)));
      oacc[n] = __builtin_amdgcn_mfma_f32_16x16x32_bf16(pf, vf, oacc[n], 0, 0, 0);
    }
  }

  float inv[4];
#pragma unroll
  for (int r = 0; r < 4; ++r) inv[r] = 1.0f / rsum[r];
#pragma unroll
  for (int r = 0; r < 4; ++r) {
    int qrow = wave * 16 + lg * 4 + r;
    float s2 = (pmk[32 + qrow] == 0.0f) ? inv[r] : 0.0f;
#pragma unroll
    for (int n = 0; n < 4; ++n)
      AO[(size_t)(b * 2048 + q0 + qrow) * 512 + h * 64 + n * 16 + lr] = (bf16)(oacc[n][r] * s2);
  }
}

// ---------------- GEMM 2 (round-4): out = AO @ Wo + bo, BM=128 BN=64 ----------------

__global__ __launch_bounds__(256) void k_gemm_out(
    const bf16* __restrict__ A, const bf16* __restrict__ BT, const float* __restrict__ bias,
    float* __restrict__ C) {
  __shared__ __align__(16) char As[16384];
  __shared__ __align__(16) char Bs[8192];
  const int m0 = blockIdx.x * 128, n0 = blockIdx.y * 64;
  const int tid = threadIdx.x, wave = tid >> 6, lane = tid & 63;
  const int wr = (wave >> 1) * 64, wc = (wave & 1) * 32;
  const int lr = lane & 15, lg = lane >> 4;
  const int srow = lane >> 3, scolb = (lane & 7) << 4;
  const char* Ab = (const char*)A;
  const char* Bb = (const char*)BT;
  f32x4 acc[4][2] = {};

  for (int kt = 0; kt < 512; kt += 64) {
    __syncthreads();
    for (int t = 0; t < 4; ++t) {
      int chunk = wave * 4 + t;
      GLD16(Ab + (size_t)(m0 + chunk * 8 + srow) * 1024 + kt * 2 + scolb,
            As + chunk * 1024);
    }
    for (int t = 0; t < 2; ++t) {
      int chunk = wave * 2 + t;
      GLD16(Bb + (size_t)(n0 + chunk * 8 + srow) * 1024 + kt * 2 + scolb,
            Bs + chunk * 1024);
    }
    __syncthreads();
    for (int kk = 0; kk < 2; ++kk) {
      bf16x8 af[4], bfr[2];
      for (int m = 0; m < 4; ++m)
        af[m] = *(const bf16x8*)(As + (wr + m * 16 + lr) * 128 + kk * 64 + lg * 16);
      for (int n = 0; n < 2; ++n)
        bfr[n] = *(const bf16x8*)(Bs + (wc + n * 16 + lr) * 128 + kk * 64 + lg * 16);
      for (int m = 0; m < 4; ++m)
        for (int n = 0; n < 2; ++n)
          acc[m][n] = __builtin_amdgcn_mfma_f32_16x16x32_bf16(af[m], bfr[n], acc[m][n], 0, 0, 0);
    }
  }

  float bv0 = bias[n0 + wc + lr], bv1 = bias[n0 + wc + 16 + lr];
  for (int m = 0; m < 4; ++m)
    for (int n = 0; n < 2; ++n)
      for (int r = 0; r < 4; ++r) {
        int gm = m0 + wr + m * 16 + lg * 4 + r;
        int gn = n0 + wc + n * 16 + lr;
        C[(size_t)gm * 512 + gn] = acc[m][n][r] + (n ? bv1 : bv0);
      }
}

// ---------------- launch ----------------

extern "C" void kernel_launch(void* const* d_in, const int* in_sizes, int n_in,
                              void* d_out, int out_size, void* d_ws, size_t ws_size,
                              hipStream_t stream) {
  const float* x     = (const float*)d_in[0];
  const int*   pmask = (const int*)d_in[1];
  const float* Wqkv  = (const float*)d_in[2];
  const float* bqkv  = (const float*)d_in[3];
  const float* Wo    = (const float*)d_in[4];
  const float* bo    = (const float*)d_in[5];
  float* out = (float*)d_out;

  char* ws = (char*)d_ws;
  bf16* xb    = (bf16*)(ws);                 // 4 MiB
  bf16* WqkvT = (bf16*)(ws + 4194304);       // 1.5 MiB (reordered)
  bf16* WoT   = (bf16*)(ws + 5767168);       // 0.5 MiB
  bf16* Qb    = (bf16*)(ws + 6291456);       // [b][h][s][d] 4 MiB
  bf16* Kb    = (bf16*)(ws + 10485760);      // [b][h][s][d] 4 MiB
  bf16* VTb   = (bf16*)(ws + 14680064);      // [b][h][d][s] 4 MiB
  bf16* AO    = (bf16*)(ws + 18874368);      // [b][s][h*d]  4 MiB

  k_prep<<<3072, 256, 0, stream>>>(x, Wqkv, Wo, xb, WqkvT, WoT);

  dim3 g1(32, 24);
  k_gemm_qkv<<<g1, 256, 0, stream>>>(xb, WqkvT, bqkv, Qb, Kb, VTb);

  dim3 ga(32, 16);
  k_attn<<<ga, 256, 0, stream>>>(Qb, Kb, VTb, pmask, AO);

  dim3 g2(32, 8);
  k_gemm_out<<<g2, 256, 0, stream>>>(AO, WoT, bo, out);
}

// Round 7
// 41.111 us; speedup vs baseline: 1.1521x; 1.0562x over previous
//
#include <hip/hip_runtime.h>
#include <hip/hip_bf16.h>

typedef __bf16 bf16;
typedef __bf16 bf16x4 __attribute__((ext_vector_type(4)));
typedef __bf16 bf16x8 __attribute__((ext_vector_type(8)));
typedef float f32x4 __attribute__((ext_vector_type(4)));

#define NEGV -9.0e15f

#define GLD16(gp, lp)                                                    \
  __builtin_amdgcn_global_load_lds(                                     \
      (const __attribute__((address_space(1))) void*)(gp),              \
      (__attribute__((address_space(3))) void*)(lp), 16, 0, 0)

// ---------------- prep: x->bf16, Wqkv^T (col-reordered), Wo^T ----------------
// Wqkv column n = h*192 + sel*64 + d  ->  n' = sel*512 + h*64 + d

__global__ __launch_bounds__(256) void k_prep(
    const float* __restrict__ x, const float* __restrict__ Wqkv, const float* __restrict__ Wo,
    bf16* __restrict__ xb, bf16* __restrict__ WqkvT, bf16* __restrict__ WoT) {
  const int bid = blockIdx.x, tid = threadIdx.x;
  if (bid < 2048) {               // x convert: 2048 * 1024 floats
    int i = bid * 1024 + tid * 4;
    float4 v = *(const float4*)(x + i);
    bf16x4 o;
    o[0] = (bf16)v.x; o[1] = (bf16)v.y; o[2] = (bf16)v.z; o[3] = (bf16)v.w;
    *(bf16x4*)(xb + i) = o;
    return;
  }
  __shared__ float tl[32][33];
  const float* src; bf16* dst; int N, t; bool remap;
  if (bid < 2816) { t = bid - 2048; src = Wqkv; dst = WqkvT; N = 1536; remap = true; }
  else            { t = bid - 2816; src = Wo;   dst = WoT;   N = 512;  remap = false; }
  const int tk = t & 15, tn = t >> 4;
  const int c = tid & 31, r0 = tid >> 5;
  for (int rr = 0; rr < 4; ++rr) {
    int row = r0 + rr * 8;
    tl[row][c] = src[(size_t)(tk * 32 + row) * N + tn * 32 + c];
  }
  __syncthreads();
  for (int rr = 0; rr < 4; ++rr) {
    int row = r0 + rr * 8;
    int nn = tn * 32 + row;
    int np = nn;
    if (remap) {
      int h = nn / 192, r2 = nn - h * 192, sel = r2 >> 6, d = r2 & 63;
      np = sel * 512 + h * 64 + d;
    }
    dst[(size_t)np * 512 + tk * 32 + c] = (bf16)tl[c][row];
  }
}

// ---------------- GEMM 1: BM=128, BN=64, 4 waves 64x32, 2-phase dbuf LDS ----------------
// Grid (32,24) = 768 = 3 blocks/CU (48KB LDS -> still 3/CU). sel: 0=Q 1=K 2=V.
// Counted-vmcnt pipeline: stage(next) issued before compute(cur); one
// vmcnt(0)+s_barrier per K-tile (T3 minimum-2-phase recipe).

__global__ __launch_bounds__(256) void k_gemm_qkv(
    const bf16* __restrict__ A, const bf16* __restrict__ BT, const float* __restrict__ bias,
    bf16* __restrict__ Qb, bf16* __restrict__ Kb, bf16* __restrict__ VTb) {
  __shared__ __align__(16) char lds[49152];  // As0@0, As1@16K, Bs0@32K, Bs1@40K
  const int m0 = blockIdx.x * 128, n0 = blockIdx.y * 64;
  const int sel = blockIdx.y >> 3;
  const bool isV = (sel == 2);
  const int tid = threadIdx.x, wave = tid >> 6, lane = tid & 63;
  const int wr = (wave >> 1) * 64, wc = (wave & 1) * 32;
  const int lr = lane & 15, lg = lane >> 4;
  const int srow = lane >> 3, scolb = (lane & 7) << 4;
  const char* Ab = (const char*)A;
  const char* Bb = (const char*)BT;
  f32x4 acc[4][2] = {};

  auto STAGE = [&](int buf, int kb) {
    char* Asb = lds + buf * 16384;
    char* Bsb = lds + 32768 + buf * 8192;
#pragma unroll
    for (int t = 0; t < 4; ++t) {
      int chunk = wave * 4 + t;
      GLD16(Ab + (size_t)(m0 + chunk * 8 + srow) * 1024 + kb + scolb, Asb + chunk * 1024);
    }
#pragma unroll
    for (int t = 0; t < 2; ++t) {
      int chunk = wave * 2 + t;
      GLD16(Bb + (size_t)(n0 + chunk * 8 + srow) * 1024 + kb + scolb, Bsb + chunk * 1024);
    }
  };

  STAGE(0, 0);
  asm volatile("s_waitcnt vmcnt(0)" ::: "memory");
  __syncthreads();

  for (int it = 0; it < 8; ++it) {
    const int cur = it & 1;
    if (it < 7) STAGE(cur ^ 1, (it + 1) * 128);
    const char* As = lds + cur * 16384;
    const char* Bs = lds + 32768 + cur * 8192;
#pragma unroll
    for (int kk = 0; kk < 2; ++kk) {
      bf16x8 af[4], bfr[2];
#pragma unroll
      for (int m = 0; m < 4; ++m)
        af[m] = *(const bf16x8*)(As + (wr + m * 16 + lr) * 128 + kk * 64 + lg * 16);
#pragma unroll
      for (int n = 0; n < 2; ++n)
        bfr[n] = *(const bf16x8*)(Bs + (wc + n * 16 + lr) * 128 + kk * 64 + lg * 16);
      if (!isV) {
#pragma unroll
        for (int m = 0; m < 4; ++m)
#pragma unroll
          for (int n = 0; n < 2; ++n)
            acc[m][n] = __builtin_amdgcn_mfma_f32_16x16x32_bf16(af[m], bfr[n], acc[m][n], 0, 0, 0);
      } else {
#pragma unroll
        for (int m = 0; m < 4; ++m)
#pragma unroll
          for (int n = 0; n < 2; ++n)
            acc[m][n] = __builtin_amdgcn_mfma_f32_16x16x32_bf16(bfr[n], af[m], acc[m][n], 0, 0, 0);
      }
    }
    if (it < 7) {
      asm volatile("s_waitcnt vmcnt(0)" ::: "memory");
      __builtin_amdgcn_s_barrier();
      asm volatile("" ::: "memory");
    }
  }

  if (!isV) {
    bf16* Dst = sel ? Kb : Qb;
    float bv[2]; int hh[2], dd[2];
#pragma unroll
    for (int n = 0; n < 2; ++n) {
      int gn = n0 + wc + n * 16 + lr;
      hh[n] = (gn >> 6) & 7; dd[n] = gn & 63;
      bv[n] = bias[hh[n] * 192 + sel * 64 + dd[n]];
    }
#pragma unroll
    for (int m = 0; m < 4; ++m)
#pragma unroll
      for (int r = 0; r < 4; ++r) {
        int gm = m0 + wr + m * 16 + lg * 4 + r;
        int b = gm >> 11, s = gm & 2047;
#pragma unroll
        for (int n = 0; n < 2; ++n) {
          float v = acc[m][n][r] + bv[n];
          Dst[((size_t)(b * 8 + hh[n]) * 2048 + s) * 64 + dd[n]] = (bf16)v;
        }
      }
  } else {
#pragma unroll
    for (int m = 0; m < 4; ++m) {
      int gm = m0 + wr + m * 16 + lr;
      int b = gm >> 11, s = gm & 2047;
#pragma unroll
      for (int n = 0; n < 2; ++n)
#pragma unroll
        for (int r = 0; r < 4; ++r) {
          int gn = n0 + wc + n * 16 + lg * 4 + r;
          int h = (gn >> 6) & 7, d = gn & 63;
          float v = acc[m][n][r] + bias[h * 192 + 128 + d];
          VTb[((size_t)(b * 8 + h) * 64 + d) * 2048 + s] = (bf16)v;
        }
    }
  }
}

// ---------------- attention ----------------
// grid (32, 16), 256 threads (4 waves). GLD16 K/V staging (round-5 proven),
// Q direct from global (no cross-wave reuse), LDS 48KB -> 3 blocks/CU.

__global__ __launch_bounds__(256) void k_attn(
    const bf16* __restrict__ Qb, const bf16* __restrict__ Kb, const bf16* __restrict__ VTb,
    const int* __restrict__ pmask, bf16* __restrict__ AO) {
  __shared__ __align__(16) char Ks[128 * 128];   // [128 keys][64 d] swizzled
  __shared__ __align__(16) char VTs[64 * 256];   // [64 d][128 s] swizzled
  __shared__ __align__(16) char Ps[64 * 256];
  __shared__ float pmk[128];   // 0 = valid key, NEGV = masked

  const int qb = blockIdx.x, bh = blockIdx.y;
  const int b = bh >> 3, h = bh & 7;
  const int q0 = qb * 64, kstart = q0 - 32;
  const int tid = threadIdx.x, wave = tid >> 6, lane = tid & 63;
  const int lr = lane & 15, lg = lane >> 4;

  const bf16* Qg = Qb + (size_t)bh * (2048 * 64);
  const bf16* Kg = Kb + (size_t)bh * (2048 * 64);
  const bf16* Vg = VTb + (size_t)bh * (64 * 2048);

  // K staging: pre-swizzled source (m173 pattern; verified round 5)
  const int srow8 = lane >> 3;
  const int srcsw8 = ((lane & 7) ^ (srow8 & 7)) << 4;
#pragma unroll
  for (int t = 0; t < 4; ++t) {
    int chunk = wave * 4 + t;
    int row = chunk * 8 + srow8;
    int sk = kstart + row;
    sk = sk < 0 ? 0 : (sk > 2047 ? 2047 : sk);
    GLD16((const char*)Kg + (size_t)sk * 128 + srcsw8, Ks + chunk * 1024);
  }
  // V^T staging
  {
    int srow4 = lane >> 4, cb = (lane & 15) << 4;
#pragma unroll
    for (int t = 0; t < 4; ++t) {
      int chunk = wave * 4 + t;
      int d = chunk * 4 + srow4;
      int csw = cb ^ ((d & 7) << 4);
      int sl = kstart + (csw >> 1);
      sl = sl < 0 ? 0 : (sl > 2040 ? 2040 : sl);
      GLD16((const char*)Vg + (size_t)d * 4096 + (size_t)sl * 2, VTs + chunk * 1024);
    }
  }
  // Q fragments direct from global — issued now, consumed after barrier
  const size_t qoff = (size_t)(q0 + wave * 16 + lr) * 64;
  bf16x8 qf0 = *(const bf16x8*)(Qg + qoff + lg * 8);
  bf16x8 qf1 = *(const bf16x8*)(Qg + qoff + 32 + lg * 8);

  if (tid < 128) {
    int sk = kstart + tid;
    pmk[tid] = (sk >= 0 && sk < 2048 && pmask[b * 2048 + sk] != 0) ? 0.0f : NEGV;
  }
  __syncthreads();

  // scores S = Q.K^T : 16 q-rows x 128 keys per wave
  const int kxor = (lr & 7) << 4;
  f32x4 sc[8] = {};
#pragma unroll
  for (int kk = 0; kk < 2; ++kk) {
    bf16x8 qf = kk ? qf1 : qf0;
    int colb = kk * 64 + lg * 16;
#pragma unroll
    for (int nt = 0; nt < 8; ++nt) {
      int krow = nt * 16 + lr;
      bf16x8 kf = *(const bf16x8*)(Ks + krow * 128 + (colb ^ kxor));
      sc[nt] = __builtin_amdgcn_mfma_f32_16x16x32_bf16(qf, kf, sc[nt], 0, 0, 0);
    }
  }

  // mask + exp, no max-subtraction (validated rounds 5/6)
  float msk[8];
#pragma unroll
  for (int nt = 0; nt < 8; ++nt) msk[nt] = pmk[nt * 16 + lr];
  float rsum[4] = {0.f, 0.f, 0.f, 0.f};
#pragma unroll
  for (int nt = 0; nt < 8; ++nt) {
    int j = nt * 16 + lr;
#pragma unroll
    for (int r = 0; r < 4; ++r) {
      int qrow = wave * 16 + lg * 4 + r;
      float v = fmaf(sc[nt][r], 0.125f, msk[nt]);
      v = ((unsigned)(j - qrow) <= 64u) ? v : NEGV;
      float p = __expf(v);
      sc[nt][r] = p;
      rsum[r] += p;
    }
  }
#pragma unroll
  for (int off = 1; off < 16; off <<= 1)
#pragma unroll
    for (int r = 0; r < 4; ++r)
      rsum[r] += __shfl_xor(rsum[r], off);
#pragma unroll
  for (int r = 0; r < 4; ++r) rsum[r] = fmaxf(rsum[r], 1e-30f);

  // unnormalized P -> LDS (bf16)
#pragma unroll
  for (int nt = 0; nt < 8; ++nt)
#pragma unroll
    for (int r = 0; r < 4; ++r) {
      int qrow = wave * 16 + lg * 4 + r;
      int colb = (nt * 16 + lr) * 2;
      *(bf16*)(Ps + qrow * 256 + (colb ^ ((qrow & 7) << 4))) = (bf16)sc[nt][r];
    }
  __syncthreads();

  // O = P.V : 16 q-rows x 64 d per wave, K=128
  f32x4 oacc[4] = {};
#pragma unroll
  for (int ks = 0; ks < 4; ++ks) {
    int colb = ks * 64 + lg * 16;
    int prow = wave * 16 + lr;
    bf16x8 pf = *(const bf16x8*)(Ps + prow * 256 + (colb ^ ((prow & 7) << 4)));
#pragma unroll
    for (int n = 0; n < 4; ++n) {
      int vrow = n * 16 + lr;
      bf16x8 vf = *(const bf16x8*)(VTs + vrow * 256 + (colb ^ ((vrow & 7) << 4)));
      oacc[n] = __builtin_amdgcn_mfma_f32_16x16x32_bf16(pf, vf, oacc[n], 0, 0, 0);
    }
  }

  float inv[4];
#pragma unroll
  for (int r = 0; r < 4; ++r) inv[r] = 1.0f / rsum[r];
#pragma unroll
  for (int r = 0; r < 4; ++r) {
    int qrow = wave * 16 + lg * 4 + r;
    float s2 = (pmk[32 + qrow] == 0.0f) ? inv[r] : 0.0f;
#pragma unroll
    for (int n = 0; n < 4; ++n)
      AO[(size_t)(b * 2048 + q0 + qrow) * 512 + h * 64 + n * 16 + lr] = (bf16)(oacc[n][r] * s2);
  }
}

// ---------------- GEMM 2: split-K 8-wave. out = AO @ Wo + bo (fp32) ----------------
// kg = wave>>2 owns K half [kg*256, kg*256+256). LDS f32x4 reduce, kg0 stores.

__global__ __launch_bounds__(512) void k_gemm_out(
    const bf16* __restrict__ A, const bf16* __restrict__ BT, const float* __restrict__ bias,
    float* __restrict__ C) {
  __shared__ __align__(16) char lds[49152];  // As[kg]@kg*16K, Bs[kg]@32K+kg*8K
  const int m0 = blockIdx.x * 128, n0 = blockIdx.y * 64;
  const int tid = threadIdx.x, wave = tid >> 6, lane = tid & 63;
  const int kg = wave >> 2, w2 = wave & 3;
  const int wr = (w2 >> 1) * 64, wc = (w2 & 1) * 32;
  const int lr = lane & 15, lg = lane >> 4;
  const int srow = lane >> 3, scolb = (lane & 7) << 4;
  const char* Ab = (const char*)A;
  const char* Bb = (const char*)BT;
  char* As = lds + kg * 16384;
  char* Bs = lds + 32768 + kg * 8192;
  f32x4 acc[4][2] = {};

  for (int it = 0; it < 4; ++it) {
    int kb = kg * 512 + it * 128;        // byte offset into K (256 elems/group)
    __syncthreads();
#pragma unroll
    for (int t = 0; t < 4; ++t) {
      int chunk = w2 * 4 + t;
      GLD16(Ab + (size_t)(m0 + chunk * 8 + srow) * 1024 + kb + scolb, As + chunk * 1024);
    }
#pragma unroll
    for (int t = 0; t < 2; ++t) {
      int chunk = w2 * 2 + t;
      GLD16(Bb + (size_t)(n0 + chunk * 8 + srow) * 1024 + kb + scolb, Bs + chunk * 1024);
    }
    __syncthreads();
#pragma unroll
    for (int kk = 0; kk < 2; ++kk) {
      bf16x8 af[4], bfr[2];
#pragma unroll
      for (int m = 0; m < 4; ++m)
        af[m] = *(const bf16x8*)(As + (wr + m * 16 + lr) * 128 + kk * 64 + lg * 16);
#pragma unroll
      for (int n = 0; n < 2; ++n)
        bfr[n] = *(const bf16x8*)(Bs + (wc + n * 16 + lr) * 128 + kk * 64 + lg * 16);
#pragma unroll
      for (int m = 0; m < 4; ++m)
#pragma unroll
        for (int n = 0; n < 2; ++n)
          acc[m][n] = __builtin_amdgcn_mfma_f32_16x16x32_bf16(af[m], bfr[n], acc[m][n], 0, 0, 0);
    }
  }

  // cross-group reduce: kg1 -> LDS, kg0 adds + stores
  __syncthreads();
  if (kg == 1) {
#pragma unroll
    for (int m = 0; m < 4; ++m)
#pragma unroll
      for (int n = 0; n < 2; ++n)
        *(f32x4*)(lds + (((m * 2 + n) * 256 + w2 * 64 + lane) << 4)) = acc[m][n];
  }
  __syncthreads();
  if (kg == 0) {
    float bv0 = bias[n0 + wc + lr], bv1 = bias[n0 + wc + 16 + lr];
#pragma unroll
    for (int m = 0; m < 4; ++m)
#pragma unroll
      for (int n = 0; n < 2; ++n) {
        acc[m][n] += *(const f32x4*)(lds + (((m * 2 + n) * 256 + w2 * 64 + lane) << 4));
#pragma unroll
        for (int r = 0; r < 4; ++r) {
          int gm = m0 + wr + m * 16 + lg * 4 + r;
          int gn = n0 + wc + n * 16 + lr;
          C[(size_t)gm * 512 + gn] = acc[m][n][r] + (n ? bv1 : bv0);
        }
      }
  }
}

// ---------------- launch ----------------

extern "C" void kernel_launch(void* const* d_in, const int* in_sizes, int n_in,
                              void* d_out, int out_size, void* d_ws, size_t ws_size,
                              hipStream_t stream) {
  const float* x     = (const float*)d_in[0];
  const int*   pmask = (const int*)d_in[1];
  const float* Wqkv  = (const float*)d_in[2];
  const float* bqkv  = (const float*)d_in[3];
  const float* Wo    = (const float*)d_in[4];
  const float* bo    = (const float*)d_in[5];
  float* out = (float*)d_out;

  char* ws = (char*)d_ws;
  bf16* xb    = (bf16*)(ws);                 // 4 MiB
  bf16* WqkvT = (bf16*)(ws + 4194304);       // 1.5 MiB (reordered)
  bf16* WoT   = (bf16*)(ws + 5767168);       // 0.5 MiB
  bf16* Qb    = (bf16*)(ws + 6291456);       // [b][h][s][d] 4 MiB
  bf16* Kb    = (bf16*)(ws + 10485760);      // [b][h][s][d] 4 MiB
  bf16* VTb   = (bf16*)(ws + 14680064);      // [b][h][d][s] 4 MiB
  bf16* AO    = (bf16*)(ws + 18874368);      // [b][s][h*d]  4 MiB

  k_prep<<<3072, 256, 0, stream>>>(x, Wqkv, Wo, xb, WqkvT, WoT);

  dim3 g1(32, 24);
  k_gemm_qkv<<<g1, 256, 0, stream>>>(xb, WqkvT, bqkv, Qb, Kb, VTb);

  dim3 ga(32, 16);
  k_attn<<<ga, 256, 0, stream>>>(Qb, Kb, VTb, pmask, AO);

  dim3 g2(32, 8);
  k_gemm_out<<<g2, 512, 0, stream>>>(AO, WoT, bo, out);
}

// Round 8
// 39.673 us; speedup vs baseline: 1.1938x; 1.0362x over previous
//
#include <hip/hip_runtime.h>
#include <hip/hip_bf16.h>

typedef __bf16 bf16;
typedef __bf16 bf16x4 __attribute__((ext_vector_type(4)));
typedef __bf16 bf16x8 __attribute__((ext_vector_type(8)));
typedef float f32x4 __attribute__((ext_vector_type(4)));

#define NEGV -9.0e15f

#define GLD16(gp, lp)                                                    \
  __builtin_amdgcn_global_load_lds(                                     \
      (const __attribute__((address_space(1))) void*)(gp),              \
      (__attribute__((address_space(3))) void*)(lp), 16, 0, 0)

// ---------------- prep: x->bf16, Wqkv^T (col-reordered), Wo^T ----------------
// Wqkv column n = h*192 + sel*64 + d  ->  n' = sel*512 + h*64 + d

__global__ __launch_bounds__(256) void k_prep(
    const float* __restrict__ x, const float* __restrict__ Wqkv, const float* __restrict__ Wo,
    bf16* __restrict__ xb, bf16* __restrict__ WqkvT, bf16* __restrict__ WoT) {
  const int bid = blockIdx.x, tid = threadIdx.x;
  if (bid < 2048) {               // x convert: 2048 * 1024 floats
    int i = bid * 1024 + tid * 4;
    float4 v = *(const float4*)(x + i);
    bf16x4 o;
    o[0] = (bf16)v.x; o[1] = (bf16)v.y; o[2] = (bf16)v.z; o[3] = (bf16)v.w;
    *(bf16x4*)(xb + i) = o;
    return;
  }
  __shared__ float tl[32][33];
  const float* src; bf16* dst; int N, t; bool remap;
  if (bid < 2816) { t = bid - 2048; src = Wqkv; dst = WqkvT; N = 1536; remap = true; }
  else            { t = bid - 2816; src = Wo;   dst = WoT;   N = 512;  remap = false; }
  const int tk = t & 15, tn = t >> 4;
  const int c = tid & 31, r0 = tid >> 5;
  for (int rr = 0; rr < 4; ++rr) {
    int row = r0 + rr * 8;
    tl[row][c] = src[(size_t)(tk * 32 + row) * N + tn * 32 + c];
  }
  __syncthreads();
  for (int rr = 0; rr < 4; ++rr) {
    int row = r0 + rr * 8;
    int nn = tn * 32 + row;
    int np = nn;
    if (remap) {
      int h = nn / 192, r2 = nn - h * 192, sel = r2 >> 6, d = r2 & 63;
      np = sel * 512 + h * 64 + d;
    }
    dst[(size_t)np * 512 + tk * 32 + c] = (bf16)tl[c][row];
  }
}

// ---------------- GEMM 1: BM=128, BN=64, 4 waves 64x32, 2-phase dbuf LDS ----------------
// Grid (32,24) = 768 = 3 blocks/CU (48KB LDS). sel: 0=Q 1=K 2=V.

__global__ __launch_bounds__(256) void k_gemm_qkv(
    const bf16* __restrict__ A, const bf16* __restrict__ BT, const float* __restrict__ bias,
    bf16* __restrict__ Qb, bf16* __restrict__ Kb, bf16* __restrict__ VTb) {
  __shared__ __align__(16) char lds[49152];  // As0@0, As1@16K, Bs0@32K, Bs1@40K
  const int m0 = blockIdx.x * 128, n0 = blockIdx.y * 64;
  const int sel = blockIdx.y >> 3;
  const bool isV = (sel == 2);
  const int tid = threadIdx.x, wave = tid >> 6, lane = tid & 63;
  const int wr = (wave >> 1) * 64, wc = (wave & 1) * 32;
  const int lr = lane & 15, lg = lane >> 4;
  const int srow = lane >> 3, scolb = (lane & 7) << 4;
  const char* Ab = (const char*)A;
  const char* Bb = (const char*)BT;
  f32x4 acc[4][2] = {};

  auto STAGE = [&](int buf, int kb) {
    char* Asb = lds + buf * 16384;
    char* Bsb = lds + 32768 + buf * 8192;
#pragma unroll
    for (int t = 0; t < 4; ++t) {
      int chunk = wave * 4 + t;
      GLD16(Ab + (size_t)(m0 + chunk * 8 + srow) * 1024 + kb + scolb, Asb + chunk * 1024);
    }
#pragma unroll
    for (int t = 0; t < 2; ++t) {
      int chunk = wave * 2 + t;
      GLD16(Bb + (size_t)(n0 + chunk * 8 + srow) * 1024 + kb + scolb, Bsb + chunk * 1024);
    }
  };

  STAGE(0, 0);
  asm volatile("s_waitcnt vmcnt(0)" ::: "memory");
  __syncthreads();

  for (int it = 0; it < 8; ++it) {
    const int cur = it & 1;
    if (it < 7) STAGE(cur ^ 1, (it + 1) * 128);
    const char* As = lds + cur * 16384;
    const char* Bs = lds + 32768 + cur * 8192;
#pragma unroll
    for (int kk = 0; kk < 2; ++kk) {
      bf16x8 af[4], bfr[2];
#pragma unroll
      for (int m = 0; m < 4; ++m)
        af[m] = *(const bf16x8*)(As + (wr + m * 16 + lr) * 128 + kk * 64 + lg * 16);
#pragma unroll
      for (int n = 0; n < 2; ++n)
        bfr[n] = *(const bf16x8*)(Bs + (wc + n * 16 + lr) * 128 + kk * 64 + lg * 16);
      if (!isV) {
#pragma unroll
        for (int m = 0; m < 4; ++m)
#pragma unroll
          for (int n = 0; n < 2; ++n)
            acc[m][n] = __builtin_amdgcn_mfma_f32_16x16x32_bf16(af[m], bfr[n], acc[m][n], 0, 0, 0);
      } else {
#pragma unroll
        for (int m = 0; m < 4; ++m)
#pragma unroll
          for (int n = 0; n < 2; ++n)
            acc[m][n] = __builtin_amdgcn_mfma_f32_16x16x32_bf16(bfr[n], af[m], acc[m][n], 0, 0, 0);
      }
    }
    if (it < 7) {
      asm volatile("s_waitcnt vmcnt(0)" ::: "memory");
      __builtin_amdgcn_s_barrier();
      asm volatile("" ::: "memory");
    }
  }

  if (!isV) {
    bf16* Dst = sel ? Kb : Qb;
    float bv[2]; int hh[2], dd[2];
#pragma unroll
    for (int n = 0; n < 2; ++n) {
      int gn = n0 + wc + n * 16 + lr;
      hh[n] = (gn >> 6) & 7; dd[n] = gn & 63;
      bv[n] = bias[hh[n] * 192 + sel * 64 + dd[n]];
    }
#pragma unroll
    for (int m = 0; m < 4; ++m)
#pragma unroll
      for (int r = 0; r < 4; ++r) {
        int gm = m0 + wr + m * 16 + lg * 4 + r;
        int b = gm >> 11, s = gm & 2047;
#pragma unroll
        for (int n = 0; n < 2; ++n) {
          float v = acc[m][n][r] + bv[n];
          Dst[((size_t)(b * 8 + hh[n]) * 2048 + s) * 64 + dd[n]] = (bf16)v;
        }
      }
  } else {
#pragma unroll
    for (int m = 0; m < 4; ++m) {
      int gm = m0 + wr + m * 16 + lr;
      int b = gm >> 11, s = gm & 2047;
#pragma unroll
      for (int n = 0; n < 2; ++n)
#pragma unroll
        for (int r = 0; r < 4; ++r) {
          int gn = n0 + wc + n * 16 + lg * 4 + r;
          int h = (gn >> 6) & 7, d = gn & 63;
          float v = acc[m][n][r] + bias[h * 192 + 128 + d];
          VTb[((size_t)(b * 8 + h) * 64 + d) * 2048 + s] = (bf16)v;
        }
    }
  }
}

// ---------------- attention ----------------
// grid (32, 16), 256 threads (4 waves). GLD16 K/V staging, Q direct from
// global, no max-sub softmax, setprio around MFMA clusters (T5, attn-positive).

__global__ __launch_bounds__(256) void k_attn(
    const bf16* __restrict__ Qb, const bf16* __restrict__ Kb, const bf16* __restrict__ VTb,
    const int* __restrict__ pmask, bf16* __restrict__ AO) {
  __shared__ __align__(16) char Ks[128 * 128];   // [128 keys][64 d] swizzled
  __shared__ __align__(16) char VTs[64 * 256];   // [64 d][128 s] swizzled
  __shared__ __align__(16) char Ps[64 * 256];
  __shared__ float pmk[128];   // 0 = valid key, NEGV = masked

  const int qb = blockIdx.x, bh = blockIdx.y;
  const int b = bh >> 3, h = bh & 7;
  const int q0 = qb * 64, kstart = q0 - 32;
  const int tid = threadIdx.x, wave = tid >> 6, lane = tid & 63;
  const int lr = lane & 15, lg = lane >> 4;

  const bf16* Qg = Qb + (size_t)bh * (2048 * 64);
  const bf16* Kg = Kb + (size_t)bh * (2048 * 64);
  const bf16* Vg = VTb + (size_t)bh * (64 * 2048);

  // K staging: pre-swizzled source (m173 pattern)
  const int srow8 = lane >> 3;
  const int srcsw8 = ((lane & 7) ^ (srow8 & 7)) << 4;
#pragma unroll
  for (int t = 0; t < 4; ++t) {
    int chunk = wave * 4 + t;
    int row = chunk * 8 + srow8;
    int sk = kstart + row;
    sk = sk < 0 ? 0 : (sk > 2047 ? 2047 : sk);
    GLD16((const char*)Kg + (size_t)sk * 128 + srcsw8, Ks + chunk * 1024);
  }
  // V^T staging
  {
    int srow4 = lane >> 4, cb = (lane & 15) << 4;
#pragma unroll
    for (int t = 0; t < 4; ++t) {
      int chunk = wave * 4 + t;
      int d = chunk * 4 + srow4;
      int csw = cb ^ ((d & 7) << 4);
      int sl = kstart + (csw >> 1);
      sl = sl < 0 ? 0 : (sl > 2040 ? 2040 : sl);
      GLD16((const char*)Vg + (size_t)d * 4096 + (size_t)sl * 2, VTs + chunk * 1024);
    }
  }
  // Q fragments direct from global — issued now, consumed after barrier
  const size_t qoff = (size_t)(q0 + wave * 16 + lr) * 64;
  bf16x8 qf0 = *(const bf16x8*)(Qg + qoff + lg * 8);
  bf16x8 qf1 = *(const bf16x8*)(Qg + qoff + 32 + lg * 8);

  if (tid < 128) {
    int sk = kstart + tid;
    pmk[tid] = (sk >= 0 && sk < 2048 && pmask[b * 2048 + sk] != 0) ? 0.0f : NEGV;
  }
  __syncthreads();

  // scores S = Q.K^T : 16 q-rows x 128 keys per wave
  const int kxor = (lr & 7) << 4;
  f32x4 sc[8] = {};
  __builtin_amdgcn_s_setprio(1);
#pragma unroll
  for (int kk = 0; kk < 2; ++kk) {
    bf16x8 qf = kk ? qf1 : qf0;
    int colb = kk * 64 + lg * 16;
#pragma unroll
    for (int nt = 0; nt < 8; ++nt) {
      int krow = nt * 16 + lr;
      bf16x8 kf = *(const bf16x8*)(Ks + krow * 128 + (colb ^ kxor));
      sc[nt] = __builtin_amdgcn_mfma_f32_16x16x32_bf16(qf, kf, sc[nt], 0, 0, 0);
    }
  }
  __builtin_amdgcn_s_setprio(0);

  // mask + exp, no max-subtraction (validated rounds 5-7)
  float msk[8];
#pragma unroll
  for (int nt = 0; nt < 8; ++nt) msk[nt] = pmk[nt * 16 + lr];
  float rsum[4] = {0.f, 0.f, 0.f, 0.f};
#pragma unroll
  for (int nt = 0; nt < 8; ++nt) {
    int j = nt * 16 + lr;
#pragma unroll
    for (int r = 0; r < 4; ++r) {
      int qrow = wave * 16 + lg * 4 + r;
      float v = fmaf(sc[nt][r], 0.125f, msk[nt]);
      v = ((unsigned)(j - qrow) <= 64u) ? v : NEGV;
      float p = __expf(v);
      sc[nt][r] = p;
      rsum[r] += p;
    }
  }
#pragma unroll
  for (int off = 1; off < 16; off <<= 1)
#pragma unroll
    for (int r = 0; r < 4; ++r)
      rsum[r] += __shfl_xor(rsum[r], off);
#pragma unroll
  for (int r = 0; r < 4; ++r) rsum[r] = fmaxf(rsum[r], 1e-30f);

  // unnormalized P -> LDS (bf16)
#pragma unroll
  for (int nt = 0; nt < 8; ++nt)
#pragma unroll
    for (int r = 0; r < 4; ++r) {
      int qrow = wave * 16 + lg * 4 + r;
      int colb = (nt * 16 + lr) * 2;
      *(bf16*)(Ps + qrow * 256 + (colb ^ ((qrow & 7) << 4))) = (bf16)sc[nt][r];
    }
  __syncthreads();

  // O = P.V : 16 q-rows x 64 d per wave, K=128
  f32x4 oacc[4] = {};
  __builtin_amdgcn_s_setprio(1);
#pragma unroll
  for (int ks = 0; ks < 4; ++ks) {
    int colb = ks * 64 + lg * 16;
    int prow = wave * 16 + lr;
    bf16x8 pf = *(const bf16x8*)(Ps + prow * 256 + (colb ^ ((prow & 7) << 4)));
#pragma unroll
    for (int n = 0; n < 4; ++n) {
      int vrow = n * 16 + lr;
      bf16x8 vf = *(const bf16x8*)(VTs + vrow * 256 + (colb ^ ((vrow & 7) << 4)));
      oacc[n] = __builtin_amdgcn_mfma_f32_16x16x32_bf16(pf, vf, oacc[n], 0, 0, 0);
    }
  }
  __builtin_amdgcn_s_setprio(0);

  float inv[4];
#pragma unroll
  for (int r = 0; r < 4; ++r) inv[r] = 1.0f / rsum[r];
#pragma unroll
  for (int r = 0; r < 4; ++r) {
    int qrow = wave * 16 + lg * 4 + r;
    float s2 = (pmk[32 + qrow] == 0.0f) ? inv[r] : 0.0f;
#pragma unroll
    for (int n = 0; n < 4; ++n)
      AO[(size_t)(b * 2048 + q0 + qrow) * 512 + h * 64 + n * 16 + lr] = (bf16)(oacc[n][r] * s2);
  }
}

// ---------------- GEMM 2: split-K 8-wave, 2-phase dbuf. out = AO @ Wo + bo ----------------
// kg = wave>>2 owns K half. LDS 96KB (still 1 block/CU at grid 256).
// A(kg,buf)@kg*16K+buf*48K ; B(kg,buf)@32K+kg*8K+buf*48K.

__global__ __launch_bounds__(512) void k_gemm_out(
    const bf16* __restrict__ A, const bf16* __restrict__ BT, const float* __restrict__ bias,
    float* __restrict__ C) {
  __shared__ __align__(16) char lds[98304];
  const int m0 = blockIdx.x * 128, n0 = blockIdx.y * 64;
  const int tid = threadIdx.x, wave = tid >> 6, lane = tid & 63;
  const int kg = wave >> 2, w2 = wave & 3;
  const int wr = (w2 >> 1) * 64, wc = (w2 & 1) * 32;
  const int lr = lane & 15, lg = lane >> 4;
  const int srow = lane >> 3, scolb = (lane & 7) << 4;
  const char* Ab = (const char*)A;
  const char* Bb = (const char*)BT;
  f32x4 acc[4][2] = {};

  auto STAGE = [&](int buf, int it) {
    char* As = lds + kg * 16384 + buf * 49152;
    char* Bs = lds + 32768 + kg * 8192 + buf * 49152;
    int kb = kg * 512 + it * 128;        // byte offset into K (256 elems/group)
#pragma unroll
    for (int t = 0; t < 4; ++t) {
      int chunk = w2 * 4 + t;
      GLD16(Ab + (size_t)(m0 + chunk * 8 + srow) * 1024 + kb + scolb, As + chunk * 1024);
    }
#pragma unroll
    for (int t = 0; t < 2; ++t) {
      int chunk = w2 * 2 + t;
      GLD16(Bb + (size_t)(n0 + chunk * 8 + srow) * 1024 + kb + scolb, Bs + chunk * 1024);
    }
  };

  STAGE(0, 0);
  asm volatile("s_waitcnt vmcnt(0)" ::: "memory");
  __syncthreads();

  for (int it = 0; it < 4; ++it) {
    const int cur = it & 1;
    if (it < 3) STAGE(cur ^ 1, it + 1);
    const char* As = lds + kg * 16384 + cur * 49152;
    const char* Bs = lds + 32768 + kg * 8192 + cur * 49152;
#pragma unroll
    for (int kk = 0; kk < 2; ++kk) {
      bf16x8 af[4], bfr[2];
#pragma unroll
      for (int m = 0; m < 4; ++m)
        af[m] = *(const bf16x8*)(As + (wr + m * 16 + lr) * 128 + kk * 64 + lg * 16);
#pragma unroll
      for (int n = 0; n < 2; ++n)
        bfr[n] = *(const bf16x8*)(Bs + (wc + n * 16 + lr) * 128 + kk * 64 + lg * 16);
#pragma unroll
      for (int m = 0; m < 4; ++m)
#pragma unroll
        for (int n = 0; n < 2; ++n)
          acc[m][n] = __builtin_amdgcn_mfma_f32_16x16x32_bf16(af[m], bfr[n], acc[m][n], 0, 0, 0);
    }
    if (it < 3) {
      asm volatile("s_waitcnt vmcnt(0)" ::: "memory");
      __builtin_amdgcn_s_barrier();
      asm volatile("" ::: "memory");
    }
  }

  // cross-group reduce: kg1 -> LDS, kg0 adds + stores
  __syncthreads();
  if (kg == 1) {
#pragma unroll
    for (int m = 0; m < 4; ++m)
#pragma unroll
      for (int n = 0; n < 2; ++n)
        *(f32x4*)(lds + (((m * 2 + n) * 256 + w2 * 64 + lane) << 4)) = acc[m][n];
  }
  __syncthreads();
  if (kg == 0) {
    float bv0 = bias[n0 + wc + lr], bv1 = bias[n0 + wc + 16 + lr];
#pragma unroll
    for (int m = 0; m < 4; ++m)
#pragma unroll
      for (int n = 0; n < 2; ++n) {
        acc[m][n] += *(const f32x4*)(lds + (((m * 2 + n) * 256 + w2 * 64 + lane) << 4));
#pragma unroll
        for (int r = 0; r < 4; ++r) {
          int gm = m0 + wr + m * 16 + lg * 4 + r;
          int gn = n0 + wc + n * 16 + lr;
          C[(size_t)gm * 512 + gn] = acc[m][n][r] + (n ? bv1 : bv0);
        }
      }
  }
}

// ---------------- launch ----------------

extern "C" void kernel_launch(void* const* d_in, const int* in_sizes, int n_in,
                              void* d_out, int out_size, void* d_ws, size_t ws_size,
                              hipStream_t stream) {
  const float* x     = (const float*)d_in[0];
  const int*   pmask = (const int*)d_in[1];
  const float* Wqkv  = (const float*)d_in[2];
  const float* bqkv  = (const float*)d_in[3];
  const float* Wo    = (const float*)d_in[4];
  const float* bo    = (const float*)d_in[5];
  float* out = (float*)d_out;

  char* ws = (char*)d_ws;
  bf16* xb    = (bf16*)(ws);                 // 4 MiB
  bf16* WqkvT = (bf16*)(ws + 4194304);       // 1.5 MiB (reordered)
  bf16* WoT   = (bf16*)(ws + 5767168);       // 0.5 MiB
  bf16* Qb    = (bf16*)(ws + 6291456);       // [b][h][s][d] 4 MiB
  bf16* Kb    = (bf16*)(ws + 10485760);      // [b][h][s][d] 4 MiB
  bf16* VTb   = (bf16*)(ws + 14680064);      // [b][h][d][s] 4 MiB
  bf16* AO    = (bf16*)(ws + 18874368);      // [b][s][h*d]  4 MiB

  k_prep<<<3072, 256, 0, stream>>>(x, Wqkv, Wo, xb, WqkvT, WoT);

  dim3 g1(32, 24);
  k_gemm_qkv<<<g1, 256, 0, stream>>>(xb, WqkvT, bqkv, Qb, Kb, VTb);

  dim3 ga(32, 16);
  k_attn<<<ga, 256, 0, stream>>>(Qb, Kb, VTb, pmask, AO);

  dim3 g2(32, 8);
  k_gemm_out<<<g2, 512, 0, stream>>>(AO, WoT, bo, out);
}